// Round 5
// baseline (3037.195 us; speedup 1.0000x reference)
//
#include <hip/hip_runtime.h>
#include <math.h>

#define BB 8
#define NN 1024
#define MM 1024
#define CC 512
#define SS 2048
#define KK 16
#define PH 64
#define AH 1024
#define COLS (NN * KK)
#define EPSV 1e-5f

typedef _Float16 half8 __attribute__((ext_vector_type(8)));
typedef _Float16 half4 __attribute__((ext_vector_type(4)));
typedef float f32x4 __attribute__((ext_vector_type(4)));

// ---------------------------------------------------------------------------
// global->LDS direct copy, 16B per lane. Dest is wave-uniform base + lane*16.
// ---------------------------------------------------------------------------
__device__ __forceinline__ void gl_lds16(const void* g, void* l) {
  __builtin_amdgcn_global_load_lds(
      (const __attribute__((address_space(1))) unsigned int*)g,
      (__attribute__((address_space(3))) unsigned int*)l, 16, 0, 0);
}

// Involution swizzle on LDS byte offsets: XOR bits 4-5 with bits 7-8.
// Makes ds_read_b128 fragment reads (16 rows x 64B-row tiles) conflict-free.
__device__ __forceinline__ int swz(int x) { return x ^ (((x >> 7) & 3) << 4); }

// Stage a 128-row x 64-byte (8KB) tile into `region` (linear LDS dest,
// pre-swizzled per-lane global source so that reads with swz() see logical).
__device__ __forceinline__ void stage_tile(const char* gbase, size_t row_stride,
                                           char* region, int t) {
  const int lane = t & 63, w = t >> 6;
#pragma unroll
  for (int pass = 0; pass < 2; ++pass) {
    int d = pass * 4096 + w * 1024 + lane * 16;
    int l = swz(d);
    gl_lds16(gbase + (size_t)(l >> 6) * row_stride + (l & 63),
             region + pass * 4096 + w * 1024);
  }
}

// Load one 16x32 fp16 MFMA fragment: lane holds row (lane&15)+rowbase,
// 8 contiguous k at chunk (lane>>4).
__device__ __forceinline__ half8 frag_ld(const char* region, int rowbase, int lane) {
  int lb = (rowbase + (lane & 15)) * 64 + (lane >> 4) * 16;
  return *(const half8*)(region + swz(lb));
}

// ---------------------------------------------------------------------------
// Kernel 1: KNN (unchanged — verified).
// ---------------------------------------------------------------------------
__global__ __launch_bounds__(256) void knn_kernel(
    const float* __restrict__ pcd, const float* __restrict__ pcd_fb,
    int* __restrict__ knn) {
  __shared__ float sx[SS], sy[SS], sz[SS], ss[SS];
  const int t = threadIdx.x;
  const int b = blockIdx.x >> 8;
  const int nbase = (blockIdx.x & 255) * 4;
  for (int s = t; s < SS; s += 256) {
    float x, y, z;
    if (s < NN) {
      x = pcd[(b * 3 + 0) * NN + s];
      y = pcd[(b * 3 + 1) * NN + s];
      z = pcd[(b * 3 + 2) * NN + s];
    } else {
      int s2 = s - NN;
      x = pcd_fb[(b * 3 + 0) * MM + s2];
      y = pcd_fb[(b * 3 + 1) * MM + s2];
      z = pcd_fb[(b * 3 + 2) * MM + s2];
    }
    sx[s] = x; sy[s] = y; sz[s] = z;
    ss[s] = x * x + y * y + z * z;
  }
  __syncthreads();
  const int wv = t >> 6, lane = t & 63;
  const int n = nbase + wv;
  const float qx = sx[n], qy = sy[n], qz = sz[n];
  const float qq = qx * qx + qy * qy + qz * qz;
  float d[32];
#pragma unroll
  for (int i = 0; i < 32; ++i) {
    int s = i * 64 + lane;
    d[i] = qq - 2.0f * (qx * sx[s] + qy * sy[s] + qz * sz[s]) + ss[s];
  }
  unsigned mask = 0;
  int win = -1;
#pragma unroll
  for (int r = 0; r < 16; ++r) {
    float best = 3.4e38f;
    int bi = 0x7fffffff;
#pragma unroll
    for (int i = 0; i < 32; ++i) {
      if (!((mask >> i) & 1) && d[i] < best) { best = d[i]; bi = i * 64 + lane; }
    }
#pragma unroll
    for (int off = 32; off >= 1; off >>= 1) {
      float ov = __shfl_xor(best, off);
      int oi = __shfl_xor(bi, off);
      if (ov < best || (ov == best && oi < bi)) { best = ov; bi = oi; }
    }
    if ((bi & 63) == lane) mask |= 1u << (bi >> 6);
    if (lane == r) win = bi;
  }
  if (lane < 16) knn[((size_t)b * NN + n) * KK + lane] = win;
}

// ---------------------------------------------------------------------------
// Kernel 2: repack attn weights to fp16 (k-contiguous rows) + fold BN1.
// ---------------------------------------------------------------------------
__global__ __launch_bounds__(256) void repack(
    const float* __restrict__ w1, const float* __restrict__ w2,
    const float* __restrict__ g, const float* __restrict__ beta,
    const float* __restrict__ m, const float* __restrict__ v,
    const float* __restrict__ b1,
    _Float16* __restrict__ w1h, _Float16* __restrict__ w2h,
    float* __restrict__ s1, float* __restrict__ t1) {
  int i = blockIdx.x * 256 + threadIdx.x;
  for (int e = i; e < AH * CC; e += gridDim.x * 256) w1h[e] = (_Float16)w1[e];
  for (int e = i; e < CC * AH; e += gridDim.x * 256) w2h[e] = (_Float16)w2[e];
  if (i < AH) {
    float sc = g[i] * rsqrtf(v[i] + EPSV);
    s1[i] = sc;
    t1[i] = (b1[i] - m[i]) * sc + beta[i];
  }
}

// ---------------------------------------------------------------------------
// Kernel 2b: per-batch transpose fusion_feat [c][s] -> FT32 [s][c] (f32).
// 64x64 tiles through LDS (pad 65 -> bank-free both phases).
// ---------------------------------------------------------------------------
__global__ __launch_bounds__(256) void transpose_feat(
    int b, const float* __restrict__ feat, const float* __restrict__ feat_fb,
    float* __restrict__ FT32) {
  __shared__ float tl[64][65];
  const int t = threadIdx.x;
  const int s0 = (blockIdx.x & 31) * 64;
  const int c0 = (blockIdx.x >> 5) * 64;
  const float* src = (s0 < NN) ? feat + (size_t)b * CC * NN + s0
                               : feat_fb + (size_t)b * CC * MM + (s0 - NN);
  const int sl = t & 63, w4 = t >> 6;
#pragma unroll
  for (int r = 0; r < 16; ++r) {
    int cl = w4 * 16 + r;
    tl[sl][cl] = src[(size_t)(c0 + cl) * NN + sl];
  }
  __syncthreads();
#pragma unroll
  for (int r = 0; r < 16; ++r) {
    int sl2 = w4 * 16 + r;
    FT32[((size_t)s0 + sl2) * CC + c0 + sl] = tl[sl2][sl];
  }
}

// ---------------------------------------------------------------------------
// Kernel 3: gather + pos MLP from FT32 rows (coalesced); writes X=[col][c]
// fp16 and V=[col][c] f32. One block per query.
// ---------------------------------------------------------------------------
__global__ __launch_bounds__(256) void build_xv(
    int b,
    const float* __restrict__ pcd, const float* __restrict__ pcd_fb,
    const float* __restrict__ FT32,
    const float* __restrict__ pw1, const float* __restrict__ pb1,
    const float* __restrict__ pg, const float* __restrict__ pbeta,
    const float* __restrict__ pm, const float* __restrict__ pv,
    const float* __restrict__ pw2, const float* __restrict__ pb2,
    const int* __restrict__ knn, _Float16* __restrict__ Xp,
    float* __restrict__ Vp) {
  __shared__ int idx_sh[KK];
  __shared__ float prel[3][KK];
  __shared__ float h1r[KK][PH + 4];
  const int t = threadIdx.x;
  const int n = blockIdx.x;
  if (t < KK) idx_sh[t] = knn[(size_t)b * COLS + n * KK + t];
  __syncthreads();
  if (t < 3 * KK) {
    int dd = t >> 4, k = t & 15;
    int s = idx_sh[k];
    float gp = (s < NN) ? pcd[(b * 3 + dd) * NN + s]
                        : pcd_fb[(b * 3 + dd) * MM + (s - NN)];
    prel[dd][k] = pcd[(b * 3 + dd) * NN + n] - gp;
  }
  __syncthreads();
  for (int e = t; e < PH * KK; e += 256) {
    int h = e >> 4, k = e & 15;
    float val = pb1[h] + pw1[h * 3 + 0] * prel[0][k] + pw1[h * 3 + 1] * prel[1][k]
              + pw1[h * 3 + 2] * prel[2][k];
    float sc = pg[h] * rsqrtf(pv[h] + EPSV);
    val = (val - pm[h]) * sc + pbeta[h];
    h1r[k][h] = fmaxf(val, 0.0f);
  }
  __syncthreads();
  const int k = t & 15, cg = t >> 4;  // this thread: neighbor k, c in [cg*32, cg*32+32)
  const int s = idx_sh[k];
  f32x4 hv[16];
#pragma unroll
  for (int q = 0; q < 16; ++q) hv[q] = *(const f32x4*)&h1r[k][q * 4];
  const float* fqrow = FT32 + (size_t)n * CC + cg * 32;   // feat[b][c][n] row-view
  const float* gfrow = FT32 + (size_t)s * CC + cg * 32;   // gathered column as row
  const size_t col = (size_t)n * KK + k;
  _Float16* xdst = Xp + col * CC + cg * 32;
  float* vdst = Vp + col * CC + cg * 32;
#pragma unroll
  for (int qq = 0; qq < 4; ++qq) {
    f32x4 fq0 = *(const f32x4*)(fqrow + qq * 8);
    f32x4 fq1 = *(const f32x4*)(fqrow + qq * 8 + 4);
    f32x4 gf0 = *(const f32x4*)(gfrow + qq * 8);
    f32x4 gf1 = *(const f32x4*)(gfrow + qq * 8 + 4);
    float fqa[8] = {fq0.x, fq0.y, fq0.z, fq0.w, fq1.x, fq1.y, fq1.z, fq1.w};
    float gfa[8] = {gf0.x, gf0.y, gf0.z, gf0.w, gf1.x, gf1.y, gf1.z, gf1.w};
    half8 xv;
    f32x4 v0, v1;
#pragma unroll
    for (int j = 0; j < 8; ++j) {
      int c = cg * 32 + qq * 8 + j;
      float pe = pb2[c];
      const f32x4* w2r = (const f32x4*)(pw2 + (size_t)c * PH);
#pragma unroll
      for (int q = 0; q < 16; ++q) {
        f32x4 w4 = w2r[q];
        pe += w4.x * hv[q].x + w4.y * hv[q].y + w4.z * hv[q].z + w4.w * hv[q].w;
      }
      xv[j] = (_Float16)(fqa[j] - gfa[j] + pe);
      float vv = gfa[j] + pe;
      if (j < 4) v0[j] = vv; else v1[j - 4] = vv;
    }
    *(half8*)(xdst + qq * 8) = xv;
    *(f32x4*)(vdst + qq * 8) = v0;
    *(f32x4*)(vdst + qq * 8 + 4) = v1;
  }
}

// ---------------------------------------------------------------------------
// Kernel 4: gemm1 = relu(bn(W1 @ X)) via f16 MFMA, 128x128 tile, BK=32.
// Epilogue transposes the tile through LDS -> A1R in [col][h] fp16 layout.
// (unchanged — verified)
// ---------------------------------------------------------------------------
__global__ __launch_bounds__(256) void gemm1_f16(
    const _Float16* __restrict__ Wh, const float* __restrict__ s1,
    const float* __restrict__ t1, const _Float16* __restrict__ Xp,
    _Float16* __restrict__ A1Rp) {
  __shared__ char lds[34816];  // 16KB staging, reused as 4x8704B transpose buf
  char* As = lds;
  char* Bs = lds + 8192;
  const int t = threadIdx.x, lane = t & 63, w = t >> 6;
  const int wr = w >> 1, wc = w & 1;
  const int h0 = blockIdx.y * 128;
  const int col0 = blockIdx.x * 128;
  f32x4 acc[4][4];
  f32x4 zz = {0.f, 0.f, 0.f, 0.f};
#pragma unroll
  for (int m = 0; m < 4; ++m)
#pragma unroll
    for (int n = 0; n < 4; ++n) acc[m][n] = zz;
  for (int s = 0; s < CC / 32; ++s) {
    const int k0 = s * 32;
    stage_tile((const char*)(Wh + (size_t)h0 * CC + k0), CC * 2, As, t);
    stage_tile((const char*)(Xp + (size_t)col0 * CC + k0), CC * 2, Bs, t);
    __syncthreads();
    half8 a[4], bf[4];
#pragma unroll
    for (int m = 0; m < 4; ++m) a[m] = frag_ld(As, wr * 64 + m * 16, lane);
#pragma unroll
    for (int n = 0; n < 4; ++n) bf[n] = frag_ld(Bs, wc * 64 + n * 16, lane);
#pragma unroll
    for (int m = 0; m < 4; ++m)
#pragma unroll
      for (int n = 0; n < 4; ++n)
        acc[m][n] = __builtin_amdgcn_mfma_f32_16x16x32_f16(a[m], bf[n], acc[m][n], 0, 0, 0);
    __syncthreads();
  }
  // Epilogue: BN+ReLU, fp16, per-wave LDS transpose ([64 col][68 h] fp16).
  char* tb = lds + w * 8704;
#pragma unroll
  for (int m = 0; m < 4; ++m) {
    float sc[4], sh[4];
#pragma unroll
    for (int r = 0; r < 4; ++r) {
      int h = h0 + wr * 64 + m * 16 + (lane >> 4) * 4 + r;
      sc[r] = s1[h];
      sh[r] = t1[h];
    }
#pragma unroll
    for (int n = 0; n < 4; ++n) {
      half4 p;
#pragma unroll
      for (int r = 0; r < 4; ++r)
        p[r] = (_Float16)fmaxf(acc[m][n][r] * sc[r] + sh[r], 0.0f);
      int col_l = n * 16 + (lane & 15);
      *(half4*)(tb + col_l * 136 + (m * 16 + (lane >> 4) * 4) * 2) = p;
    }
  }
  __syncthreads();
  char* dstbase = (char*)A1Rp + (size_t)(h0 + wr * 64) * 2;
#pragma unroll
  for (int pass = 0; pass < 8; ++pass) {
    int col_l = (lane >> 3) + pass * 8;
    int chunk = lane & 7;
    *(half8*)(dstbase + (size_t)(col0 + wc * 64 + col_l) * (AH * 2) + chunk * 16) =
        *(const half8*)(tb + col_l * 136 + chunk * 16);
  }
}

// ---------------------------------------------------------------------------
// Kernel 5: gemm2 = W2 @ A1R via f16 MFMA; fused softmax(K=16) + V-weighted
// sum epilogue. V now [col][c] f32 -> one f32x4 load per fragment.
// ---------------------------------------------------------------------------
__global__ __launch_bounds__(256) void gemm2_f16(
    int b, const _Float16* __restrict__ Wh, const _Float16* __restrict__ A1Rp,
    const float* __restrict__ Vp, float* __restrict__ out) {
  __shared__ char lds[16384];
  char* As = lds;
  char* Bs = lds + 8192;
  const int t = threadIdx.x, lane = t & 63, w = t >> 6;
  const int wr = w >> 1, wc = w & 1;
  const int c0 = blockIdx.y * 128;
  const int col0 = blockIdx.x * 128;
  f32x4 acc[4][4];
  f32x4 zz = {0.f, 0.f, 0.f, 0.f};
#pragma unroll
  for (int m = 0; m < 4; ++m)
#pragma unroll
    for (int n = 0; n < 4; ++n) acc[m][n] = zz;
  for (int s = 0; s < AH / 32; ++s) {
    const int k0 = s * 32;
    stage_tile((const char*)(Wh + (size_t)c0 * AH + k0), AH * 2, As, t);
    stage_tile((const char*)(A1Rp + (size_t)col0 * AH + k0), AH * 2, Bs, t);
    __syncthreads();
    half8 a[4], bf[4];
#pragma unroll
    for (int m = 0; m < 4; ++m) a[m] = frag_ld(As, wr * 64 + m * 16, lane);
#pragma unroll
    for (int n = 0; n < 4; ++n) bf[n] = frag_ld(Bs, wc * 64 + n * 16, lane);
#pragma unroll
    for (int m = 0; m < 4; ++m)
#pragma unroll
      for (int n = 0; n < 4; ++n)
        acc[m][n] = __builtin_amdgcn_mfma_f32_16x16x32_f16(a[m], bf[n], acc[m][n], 0, 0, 0);
    __syncthreads();
  }
  // Fused softmax + weighted-V epilogue. Lanes sharing (lane>>4) hold the 16
  // neighbors (lane&15 = k) of one (c, query) pair.
#pragma unroll
  for (int m = 0; m < 4; ++m)
#pragma unroll
    for (int n = 0; n < 4; ++n) {
      int cg2 = col0 + wc * 64 + n * 16 + (lane & 15);
      int nq = cg2 >> 4;
      int cbase = c0 + wr * 64 + m * 16 + (lane >> 4) * 4;
      f32x4 v4 = *(const f32x4*)(Vp + (size_t)cg2 * CC + cbase);
#pragma unroll
      for (int r = 0; r < 4; ++r) {
        float e = __expf(acc[m][n][r]);
        float se = e;
#pragma unroll
        for (int o = 8; o >= 1; o >>= 1) se += __shfl_xor(se, o);
        float te = e * v4[r];
#pragma unroll
        for (int o = 8; o >= 1; o >>= 1) te += __shfl_xor(te, o);
        if ((lane & 15) == 0)
          out[((size_t)b * CC + cbase + r) * NN + nq] = __fdividef(te, se);
      }
    }
}

// ---------------------------------------------------------------------------
extern "C" void kernel_launch(void* const* d_in, const int* in_sizes, int n_in,
                              void* d_out, int out_size, void* d_ws, size_t ws_size,
                              hipStream_t stream) {
  const float* pcd     = (const float*)d_in[0];
  const float* feat    = (const float*)d_in[1];
  const float* pcd_fb  = (const float*)d_in[2];
  const float* feat_fb = (const float*)d_in[3];
  const float* pw1     = (const float*)d_in[4];
  const float* pb1     = (const float*)d_in[5];
  const float* pg      = (const float*)d_in[6];
  const float* pbeta   = (const float*)d_in[7];
  const float* pm      = (const float*)d_in[8];
  const float* pv      = (const float*)d_in[9];
  const float* pw2     = (const float*)d_in[10];
  const float* pb2     = (const float*)d_in[11];
  const float* aw1     = (const float*)d_in[12];
  const float* ab1     = (const float*)d_in[13];
  const float* ag      = (const float*)d_in[14];
  const float* abeta   = (const float*)d_in[15];
  const float* am      = (const float*)d_in[16];
  const float* av      = (const float*)d_in[17];
  const float* aw2     = (const float*)d_in[18];
  const float* ab2     = (const float*)d_in[19];
  (void)ab2;  // cancels in softmax
  float* out = (float*)d_out;

  char* ws = (char*)d_ws;
  size_t off = 0;
  int* idx_ws = (int*)(ws + off);      off += (size_t)BB * NN * KK * sizeof(int);
  _Float16* W1h = (_Float16*)(ws + off); off += (size_t)AH * CC * 2;
  _Float16* W2h = (_Float16*)(ws + off); off += (size_t)CC * AH * 2;
  float* s1 = (float*)(ws + off);      off += AH * sizeof(float);
  float* t1 = (float*)(ws + off);      off += AH * sizeof(float);
  off = (off + 255) & ~(size_t)255;
  float* FT32 = (float*)(ws + off);       off += (size_t)SS * CC * 4;      //  4.2 MB
  _Float16* Xp = (_Float16*)(ws + off);   off += (size_t)COLS * CC * 2;    // 16.8 MB
  _Float16* A1Rp = (_Float16*)(ws + off); off += (size_t)COLS * AH * 2;    // 33.6 MB
  float* Vp = (float*)(ws + off);         off += (size_t)COLS * CC * 4;    // 33.6 MB

  knn_kernel<<<dim3(BB * NN / 4), 256, 0, stream>>>(pcd, pcd_fb, idx_ws);
  repack<<<dim3(512), 256, 0, stream>>>(aw1, aw2, ag, abeta, am, av, ab1,
                                        W1h, W2h, s1, t1);
  for (int b = 0; b < BB; ++b) {
    transpose_feat<<<dim3(256), 256, 0, stream>>>(b, feat, feat_fb, FT32);
    build_xv<<<dim3(NN), 256, 0, stream>>>(
        b, pcd, pcd_fb, FT32,
        pw1, pb1, pg, pbeta, pm, pv, pw2, pb2, idx_ws, Xp, Vp);
    gemm1_f16<<<dim3(COLS / 128, AH / 128), 256, 0, stream>>>(W1h, s1, t1, Xp, A1Rp);
    gemm2_f16<<<dim3(COLS / 128, CC / 128), 256, 0, stream>>>(b, W2h, A1Rp, Vp, out);
  }
}

// Round 6
// 1032.462 us; speedup vs baseline: 2.9417x; 2.9417x over previous
//
#include <hip/hip_runtime.h>
#include <math.h>

#define BB 8
#define NN 1024
#define MM 1024
#define CC 512
#define SS 2048
#define KK 16
#define PH 64
#define AH 1024
#define COLS (NN * KK)
#define EPSV 1e-5f

typedef _Float16 half8 __attribute__((ext_vector_type(8)));
typedef _Float16 half4 __attribute__((ext_vector_type(4)));
typedef _Float16 half2v __attribute__((ext_vector_type(2)));
typedef float f32x4 __attribute__((ext_vector_type(4)));
typedef float f32x2 __attribute__((ext_vector_type(2)));

// ---------------------------------------------------------------------------
// global->LDS direct copy, 16B per lane. Dest is wave-uniform base + lane*16.
// ---------------------------------------------------------------------------
__device__ __forceinline__ void gl_lds16(const void* g, void* l) {
  __builtin_amdgcn_global_load_lds(
      (const __attribute__((address_space(1))) unsigned int*)g,
      (__attribute__((address_space(3))) unsigned int*)l, 16, 0, 0);
}

// Involution swizzle on LDS byte offsets: XOR bits 4-5 with bits 7-8.
__device__ __forceinline__ int swz(int x) { return x ^ (((x >> 7) & 3) << 4); }

// Stage a 128-row x 64-byte (8KB) tile into `region` (linear LDS dest,
// pre-swizzled per-lane global source so that reads with swz() see logical).
__device__ __forceinline__ void stage_tile(const char* gbase, size_t row_stride,
                                           char* region, int t) {
  const int lane = t & 63, w = t >> 6;
#pragma unroll
  for (int pass = 0; pass < 2; ++pass) {
    int d = pass * 4096 + w * 1024 + lane * 16;
    int l = swz(d);
    gl_lds16(gbase + (size_t)(l >> 6) * row_stride + (l & 63),
             region + pass * 4096 + w * 1024);
  }
}

__device__ __forceinline__ half8 frag_ld(const char* region, int rowbase, int lane) {
  int lb = (rowbase + (lane & 15)) * 64 + (lane >> 4) * 16;
  return *(const half8*)(region + swz(lb));
}

// ---------------------------------------------------------------------------
// Kernel 1: KNN (unchanged — verified).
// ---------------------------------------------------------------------------
__global__ __launch_bounds__(256) void knn_kernel(
    const float* __restrict__ pcd, const float* __restrict__ pcd_fb,
    int* __restrict__ knn) {
  __shared__ float sx[SS], sy[SS], sz[SS], ss[SS];
  const int t = threadIdx.x;
  const int b = blockIdx.x >> 8;
  const int nbase = (blockIdx.x & 255) * 4;
  for (int s = t; s < SS; s += 256) {
    float x, y, z;
    if (s < NN) {
      x = pcd[(b * 3 + 0) * NN + s];
      y = pcd[(b * 3 + 1) * NN + s];
      z = pcd[(b * 3 + 2) * NN + s];
    } else {
      int s2 = s - NN;
      x = pcd_fb[(b * 3 + 0) * MM + s2];
      y = pcd_fb[(b * 3 + 1) * MM + s2];
      z = pcd_fb[(b * 3 + 2) * MM + s2];
    }
    sx[s] = x; sy[s] = y; sz[s] = z;
    ss[s] = x * x + y * y + z * z;
  }
  __syncthreads();
  const int wv = t >> 6, lane = t & 63;
  const int n = nbase + wv;
  const float qx = sx[n], qy = sy[n], qz = sz[n];
  const float qq = qx * qx + qy * qy + qz * qz;
  float d[32];
#pragma unroll
  for (int i = 0; i < 32; ++i) {
    int s = i * 64 + lane;
    d[i] = qq - 2.0f * (qx * sx[s] + qy * sy[s] + qz * sz[s]) + ss[s];
  }
  unsigned mask = 0;
  int win = -1;
#pragma unroll
  for (int r = 0; r < 16; ++r) {
    float best = 3.4e38f;
    int bi = 0x7fffffff;
#pragma unroll
    for (int i = 0; i < 32; ++i) {
      if (!((mask >> i) & 1) && d[i] < best) { best = d[i]; bi = i * 64 + lane; }
    }
#pragma unroll
    for (int off = 32; off >= 1; off >>= 1) {
      float ov = __shfl_xor(best, off);
      int oi = __shfl_xor(bi, off);
      if (ov < best || (ov == best && oi < bi)) { best = ov; bi = oi; }
    }
    if ((bi & 63) == lane) mask |= 1u << (bi >> 6);
    if (lane == r) win = bi;
  }
  if (lane < 16) knn[((size_t)b * NN + n) * KK + lane] = win;
}

// ---------------------------------------------------------------------------
// Kernel 2: repack attn weights to fp16 (k-contiguous rows) + fold BN1.
// ---------------------------------------------------------------------------
__global__ __launch_bounds__(256) void repack(
    const float* __restrict__ w1, const float* __restrict__ w2,
    const float* __restrict__ g, const float* __restrict__ beta,
    const float* __restrict__ m, const float* __restrict__ v,
    const float* __restrict__ b1,
    _Float16* __restrict__ w1h, _Float16* __restrict__ w2h,
    float* __restrict__ s1, float* __restrict__ t1) {
  int i = blockIdx.x * 256 + threadIdx.x;
  for (int e = i; e < AH * CC; e += gridDim.x * 256) w1h[e] = (_Float16)w1[e];
  for (int e = i; e < CC * AH; e += gridDim.x * 256) w2h[e] = (_Float16)w2[e];
  if (i < AH) {
    float sc = g[i] * rsqrtf(v[i] + EPSV);
    s1[i] = sc;
    t1[i] = (b1[i] - m[i]) * sc + beta[i];
  }
}

// ---------------------------------------------------------------------------
// Kernel 2b: per-batch transpose fusion_feat [c][s] -> FT32 [s][c] (f32).
// (unchanged — verified in round 5)
// ---------------------------------------------------------------------------
__global__ __launch_bounds__(256) void transpose_feat(
    int b, const float* __restrict__ feat, const float* __restrict__ feat_fb,
    float* __restrict__ FT32) {
  __shared__ float tl[64][65];
  const int t = threadIdx.x;
  const int s0 = (blockIdx.x & 31) * 64;
  const int c0 = (blockIdx.x >> 5) * 64;
  const float* src = (s0 < NN) ? feat + (size_t)b * CC * NN + s0
                               : feat_fb + (size_t)b * CC * MM + (s0 - NN);
  const int sl = t & 63, w4 = t >> 6;
#pragma unroll
  for (int r = 0; r < 16; ++r) {
    int cl = w4 * 16 + r;
    tl[sl][cl] = src[(size_t)(c0 + cl) * NN + sl];
  }
  __syncthreads();
#pragma unroll
  for (int r = 0; r < 16; ++r) {
    int sl2 = w4 * 16 + r;
    FT32[((size_t)s0 + sl2) * CC + c0 + sl] = tl[sl2][sl];
  }
}

// ---------------------------------------------------------------------------
// Kernel 3: gather + pos MLP, two-phase, spill-free.
// Phase A: thread t owns channels {t, t+256}; pe accumulators in registers
//          (static unrolled k indexing only); result -> pe_lds[16][520].
// Phase B: per k, fully coalesced streaming: X=[col][c] fp16, V=[col][c] f32.
// ---------------------------------------------------------------------------
__global__ __launch_bounds__(256) void build_xv(
    int b,
    const float* __restrict__ pcd, const float* __restrict__ pcd_fb,
    const float* __restrict__ FT32,
    const float* __restrict__ pw1, const float* __restrict__ pb1,
    const float* __restrict__ pg, const float* __restrict__ pbeta,
    const float* __restrict__ pm, const float* __restrict__ pv,
    const float* __restrict__ pw2, const float* __restrict__ pb2,
    const int* __restrict__ knn, _Float16* __restrict__ Xp,
    float* __restrict__ Vp) {
  __shared__ int idx_sh[KK];
  __shared__ float prel[3][KK];
  __shared__ float h1r[KK][PH + 4];
  __shared__ float pe_lds[KK][520];
  const int t = threadIdx.x;
  const int n = blockIdx.x;
  if (t < KK) idx_sh[t] = knn[(size_t)b * COLS + n * KK + t];
  __syncthreads();
  if (t < 3 * KK) {
    int dd = t >> 4, k = t & 15;
    int s = idx_sh[k];
    float gp = (s < NN) ? pcd[(b * 3 + dd) * NN + s]
                        : pcd_fb[(b * 3 + dd) * MM + (s - NN)];
    prel[dd][k] = pcd[(b * 3 + dd) * NN + n] - gp;
  }
  __syncthreads();
  for (int e = t; e < PH * KK; e += 256) {
    int h = e >> 4, k = e & 15;
    float val = pb1[h] + pw1[h * 3 + 0] * prel[0][k] + pw1[h * 3 + 1] * prel[1][k]
              + pw1[h * 3 + 2] * prel[2][k];
    float sc = pg[h] * rsqrtf(pv[h] + EPSV);
    val = (val - pm[h]) * sc + pbeta[h];
    h1r[k][h] = fmaxf(val, 0.0f);
  }
  __syncthreads();
  // ---- Phase A: pe[k] for channels c0=t and c1=t+256 -----------------------
  float pe0[KK], pe1[KK];
#pragma unroll
  for (int k = 0; k < KK; ++k) { pe0[k] = 0.0f; pe1[k] = 0.0f; }
  const float* w2r0 = pw2 + (size_t)t * PH;
  const float* w2r1 = pw2 + (size_t)(t + 256) * PH;
  for (int hq = 0; hq < PH / 4; ++hq) {
    f32x4 wa = *(const f32x4*)(w2r0 + hq * 4);
    f32x4 wb = *(const f32x4*)(w2r1 + hq * 4);
#pragma unroll
    for (int k = 0; k < KK; ++k) {
      f32x4 hk = *(const f32x4*)&h1r[k][hq * 4];  // wave-uniform -> broadcast
      pe0[k] += wa.x * hk.x + wa.y * hk.y + wa.z * hk.z + wa.w * hk.w;
      pe1[k] += wb.x * hk.x + wb.y * hk.y + wb.z * hk.z + wb.w * hk.w;
    }
  }
  {
    float bb0 = pb2[t], bb1 = pb2[t + 256];
#pragma unroll
    for (int k = 0; k < KK; ++k) {
      pe_lds[k][t] = pe0[k] + bb0;        // lanes adjacent -> conflict-free
      pe_lds[k][t + 256] = pe1[k] + bb1;
    }
  }
  __syncthreads();
  // ---- Phase B: coalesced gather + X/V stream ------------------------------
  f32x2 fqv = *(const f32x2*)(FT32 + (size_t)n * CC + 2 * t);
  for (int k = 0; k < KK; ++k) {
    int s = idx_sh[k];
    f32x2 gfv = *(const f32x2*)(FT32 + (size_t)s * CC + 2 * t);
    f32x2 pe2 = *(const f32x2*)&pe_lds[k][2 * t];
    size_t col = (size_t)n * KK + k;
    half2v xo;
    xo[0] = (_Float16)(fqv[0] - gfv[0] + pe2[0]);
    xo[1] = (_Float16)(fqv[1] - gfv[1] + pe2[1]);
    *(half2v*)(Xp + col * CC + 2 * t) = xo;
    f32x2 vo;
    vo[0] = gfv[0] + pe2[0];
    vo[1] = gfv[1] + pe2[1];
    *(f32x2*)(Vp + col * CC + 2 * t) = vo;
  }
}

// ---------------------------------------------------------------------------
// Kernel 4: gemm1 = relu(bn(W1 @ X)) via f16 MFMA, 128x128 tile, BK=32.
// (unchanged — verified)
// ---------------------------------------------------------------------------
__global__ __launch_bounds__(256) void gemm1_f16(
    const _Float16* __restrict__ Wh, const float* __restrict__ s1,
    const float* __restrict__ t1, const _Float16* __restrict__ Xp,
    _Float16* __restrict__ A1Rp) {
  __shared__ char lds[34816];  // 16KB staging, reused as 4x8704B transpose buf
  char* As = lds;
  char* Bs = lds + 8192;
  const int t = threadIdx.x, lane = t & 63, w = t >> 6;
  const int wr = w >> 1, wc = w & 1;
  const int h0 = blockIdx.y * 128;
  const int col0 = blockIdx.x * 128;
  f32x4 acc[4][4];
  f32x4 zz = {0.f, 0.f, 0.f, 0.f};
#pragma unroll
  for (int m = 0; m < 4; ++m)
#pragma unroll
    for (int n = 0; n < 4; ++n) acc[m][n] = zz;
  for (int s = 0; s < CC / 32; ++s) {
    const int k0 = s * 32;
    stage_tile((const char*)(Wh + (size_t)h0 * CC + k0), CC * 2, As, t);
    stage_tile((const char*)(Xp + (size_t)col0 * CC + k0), CC * 2, Bs, t);
    __syncthreads();
    half8 a[4], bf[4];
#pragma unroll
    for (int m = 0; m < 4; ++m) a[m] = frag_ld(As, wr * 64 + m * 16, lane);
#pragma unroll
    for (int n = 0; n < 4; ++n) bf[n] = frag_ld(Bs, wc * 64 + n * 16, lane);
#pragma unroll
    for (int m = 0; m < 4; ++m)
#pragma unroll
      for (int n = 0; n < 4; ++n)
        acc[m][n] = __builtin_amdgcn_mfma_f32_16x16x32_f16(a[m], bf[n], acc[m][n], 0, 0, 0);
    __syncthreads();
  }
  // Epilogue: BN+ReLU, fp16, per-wave LDS transpose ([64 col][68 h] fp16).
  char* tb = lds + w * 8704;
#pragma unroll
  for (int m = 0; m < 4; ++m) {
    float sc[4], sh[4];
#pragma unroll
    for (int r = 0; r < 4; ++r) {
      int h = h0 + wr * 64 + m * 16 + (lane >> 4) * 4 + r;
      sc[r] = s1[h];
      sh[r] = t1[h];
    }
#pragma unroll
    for (int n = 0; n < 4; ++n) {
      half4 p;
#pragma unroll
      for (int r = 0; r < 4; ++r)
        p[r] = (_Float16)fmaxf(acc[m][n][r] * sc[r] + sh[r], 0.0f);
      int col_l = n * 16 + (lane & 15);
      *(half4*)(tb + col_l * 136 + (m * 16 + (lane >> 4) * 4) * 2) = p;
    }
  }
  __syncthreads();
  char* dstbase = (char*)A1Rp + (size_t)(h0 + wr * 64) * 2;
#pragma unroll
  for (int pass = 0; pass < 8; ++pass) {
    int col_l = (lane >> 3) + pass * 8;
    int chunk = lane & 7;
    *(half8*)(dstbase + (size_t)(col0 + wc * 64 + col_l) * (AH * 2) + chunk * 16) =
        *(const half8*)(tb + col_l * 136 + chunk * 16);
  }
}

// ---------------------------------------------------------------------------
// Kernel 5: gemm2 = W2 @ A1R via f16 MFMA; fused softmax(K=16) + V-weighted
// sum epilogue. V is [col][c] f32 -> one f32x4 load per fragment.
// (unchanged — verified in round 5)
// ---------------------------------------------------------------------------
__global__ __launch_bounds__(256) void gemm2_f16(
    int b, const _Float16* __restrict__ Wh, const _Float16* __restrict__ A1Rp,
    const float* __restrict__ Vp, float* __restrict__ out) {
  __shared__ char lds[16384];
  char* As = lds;
  char* Bs = lds + 8192;
  const int t = threadIdx.x, lane = t & 63, w = t >> 6;
  const int wr = w >> 1, wc = w & 1;
  const int c0 = blockIdx.y * 128;
  const int col0 = blockIdx.x * 128;
  f32x4 acc[4][4];
  f32x4 zz = {0.f, 0.f, 0.f, 0.f};
#pragma unroll
  for (int m = 0; m < 4; ++m)
#pragma unroll
    for (int n = 0; n < 4; ++n) acc[m][n] = zz;
  for (int s = 0; s < AH / 32; ++s) {
    const int k0 = s * 32;
    stage_tile((const char*)(Wh + (size_t)c0 * AH + k0), AH * 2, As, t);
    stage_tile((const char*)(A1Rp + (size_t)col0 * AH + k0), AH * 2, Bs, t);
    __syncthreads();
    half8 a[4], bf[4];
#pragma unroll
    for (int m = 0; m < 4; ++m) a[m] = frag_ld(As, wr * 64 + m * 16, lane);
#pragma unroll
    for (int n = 0; n < 4; ++n) bf[n] = frag_ld(Bs, wc * 64 + n * 16, lane);
#pragma unroll
    for (int m = 0; m < 4; ++m)
#pragma unroll
      for (int n = 0; n < 4; ++n)
        acc[m][n] = __builtin_amdgcn_mfma_f32_16x16x32_f16(a[m], bf[n], acc[m][n], 0, 0, 0);
    __syncthreads();
  }
#pragma unroll
  for (int m = 0; m < 4; ++m)
#pragma unroll
    for (int n = 0; n < 4; ++n) {
      int cg2 = col0 + wc * 64 + n * 16 + (lane & 15);
      int nq = cg2 >> 4;
      int cbase = c0 + wr * 64 + m * 16 + (lane >> 4) * 4;
      f32x4 v4 = *(const f32x4*)(Vp + (size_t)cg2 * CC + cbase);
#pragma unroll
      for (int r = 0; r < 4; ++r) {
        float e = __expf(acc[m][n][r]);
        float se = e;
#pragma unroll
        for (int o = 8; o >= 1; o >>= 1) se += __shfl_xor(se, o);
        float te = e * v4[r];
#pragma unroll
        for (int o = 8; o >= 1; o >>= 1) te += __shfl_xor(te, o);
        if ((lane & 15) == 0)
          out[((size_t)b * CC + cbase + r) * NN + nq] = __fdividef(te, se);
      }
    }
}

// ---------------------------------------------------------------------------
extern "C" void kernel_launch(void* const* d_in, const int* in_sizes, int n_in,
                              void* d_out, int out_size, void* d_ws, size_t ws_size,
                              hipStream_t stream) {
  const float* pcd     = (const float*)d_in[0];
  const float* feat    = (const float*)d_in[1];
  const float* pcd_fb  = (const float*)d_in[2];
  const float* feat_fb = (const float*)d_in[3];
  const float* pw1     = (const float*)d_in[4];
  const float* pb1     = (const float*)d_in[5];
  const float* pg      = (const float*)d_in[6];
  const float* pbeta   = (const float*)d_in[7];
  const float* pm      = (const float*)d_in[8];
  const float* pv      = (const float*)d_in[9];
  const float* pw2     = (const float*)d_in[10];
  const float* pb2     = (const float*)d_in[11];
  const float* aw1     = (const float*)d_in[12];
  const float* ab1     = (const float*)d_in[13];
  const float* ag      = (const float*)d_in[14];
  const float* abeta   = (const float*)d_in[15];
  const float* am      = (const float*)d_in[16];
  const float* av      = (const float*)d_in[17];
  const float* aw2     = (const float*)d_in[18];
  const float* ab2     = (const float*)d_in[19];
  (void)ab2;  // cancels in softmax
  float* out = (float*)d_out;

  char* ws = (char*)d_ws;
  size_t off = 0;
  int* idx_ws = (int*)(ws + off);      off += (size_t)BB * NN * KK * sizeof(int);
  _Float16* W1h = (_Float16*)(ws + off); off += (size_t)AH * CC * 2;
  _Float16* W2h = (_Float16*)(ws + off); off += (size_t)CC * AH * 2;
  float* s1 = (float*)(ws + off);      off += AH * sizeof(float);
  float* t1 = (float*)(ws + off);      off += AH * sizeof(float);
  off = (off + 255) & ~(size_t)255;
  float* FT32 = (float*)(ws + off);       off += (size_t)SS * CC * 4;      //  4.2 MB
  _Float16* Xp = (_Float16*)(ws + off);   off += (size_t)COLS * CC * 2;    // 16.8 MB
  _Float16* A1Rp = (_Float16*)(ws + off); off += (size_t)COLS * AH * 2;    // 33.6 MB
  float* Vp = (float*)(ws + off);         off += (size_t)COLS * CC * 4;    // 33.6 MB

  knn_kernel<<<dim3(BB * NN / 4), 256, 0, stream>>>(pcd, pcd_fb, idx_ws);
  repack<<<dim3(512), 256, 0, stream>>>(aw1, aw2, ag, abeta, am, av, ab1,
                                        W1h, W2h, s1, t1);
  for (int b = 0; b < BB; ++b) {
    transpose_feat<<<dim3(256), 256, 0, stream>>>(b, feat, feat_fb, FT32);
    build_xv<<<dim3(NN), 256, 0, stream>>>(
        b, pcd, pcd_fb, FT32,
        pw1, pb1, pg, pbeta, pm, pv, pw2, pb2, idx_ws, Xp, Vp);
    gemm1_f16<<<dim3(COLS / 128, AH / 128), 256, 0, stream>>>(W1h, s1, t1, Xp, A1Rp);
    gemm2_f16<<<dim3(COLS / 128, CC / 128), 256, 0, stream>>>(b, W2h, A1Rp, Vp, out);
  }
}